// Round 2
// baseline (151.119 us; speedup 1.0000x reference)
//
#include <hip/hip_runtime.h>

// Xd qudit shift on wire 3 of an 8-wire dim-8 register:
//   out[a,j,b] = x[a,(8-j)%8,b],  pre=512, DIM=8, post=4096 (B=1 folded in).
// Linear index n: digit j = (n>>12)&7. Pure permutation copy, contiguity in b
// (4096 floats) preserved -> fully coalesced float4 loads/stores.
//
// Harness evidence (round 1 core dump + out_npz size = in/2): d_out holds
// out_size = N float32 elements (real part of the complex64 reference).
// Defensive: also handle out_size == 2N (interleaved complex) just in case.

__global__ void Xd_real_kernel(const float* __restrict__ xr,
                               float4* __restrict__ out,
                               int n_quads /* N/4 */) {
    int t = blockIdx.x * blockDim.x + threadIdx.x;
    if (t >= n_quads) return;
    int n = t << 2;                      // first element index (multiple of 4)
    int j = (n >> 12) & 7;               // wire-3 digit (post = 4096 = 2^12)
    int jp = (8 - j) & 7;                // source digit
    int src = n + ((jp - j) << 12);      // same a,b; swap j digit

    out[t] = *reinterpret_cast<const float4*>(xr + src);
}

__global__ void Xd_cplx_kernel(const float* __restrict__ xr,
                               const float* __restrict__ xi,
                               float4* __restrict__ out,
                               int n_pairs /* N/2 */) {
    int t = blockIdx.x * blockDim.x + threadIdx.x;
    if (t >= n_pairs) return;
    int n = t << 1;
    int j = (n >> 12) & 7;
    int jp = (8 - j) & 7;
    int src = n + ((jp - j) << 12);

    float2 r  = *reinterpret_cast<const float2*>(xr + src);
    float2 im = *reinterpret_cast<const float2*>(xi + src);
    out[t] = make_float4(r.x, im.x, r.y, im.y);
}

extern "C" void kernel_launch(void* const* d_in, const int* in_sizes, int n_in,
                              void* d_out, int out_size, void* d_ws, size_t ws_size,
                              hipStream_t stream) {
    const float* xr = (const float*)d_in[0];
    const float* xi = (const float*)d_in[1];
    float4* out = (float4*)d_out;

    int N = in_sizes[0];                 // 8^8 = 16,777,216
    int block = 256;

    if (out_size == N) {
        // float32 output: permuted real plane only (64 MB in + 64 MB out)
        int n_quads = N >> 2;
        int grid = (n_quads + block - 1) / block;
        Xd_real_kernel<<<grid, block, 0, stream>>>(xr, out, n_quads);
    } else {
        // interleaved complex64 output (out_size == 2N floats)
        int n_pairs = N >> 1;
        int grid = (n_pairs + block - 1) / block;
        Xd_cplx_kernel<<<grid, block, 0, stream>>>(xr, xi, out, n_pairs);
    }
}

// Round 5
// 147.594 us; speedup vs baseline: 1.0239x; 1.0239x over previous
//
#include <hip/hip_runtime.h>

// Xd qudit shift on wire 3 of an 8-wire dim-8 register:
//   out[a,j,b] = x[a,(8-j)%8,b],  pre=512, DIM=8, post=4096.
// Pure permutation copy; output is float32 (real plane), out_size == N.
// Linear index n: digit j = (n>>12)&7; src = n + (((8-j)&7) - j)*4096.
// Contiguity in b (4096 floats) preserved -> fully coalesced 16B/lane both
// ways, j uniform within a wave -> no divergence. Nontemporal hints keep the
// touch-once streams from thrashing L2. Note: the nontemporal builtins need a
// NATIVE clang vector type (ext_vector_type), not HIP_vector_type<float,4>.

typedef float f32x4 __attribute__((ext_vector_type(4)));

__global__ void Xd_real_kernel(const float* __restrict__ xr,
                               f32x4* __restrict__ out,
                               int n_quads /* N/4 */) {
    int t = blockIdx.x * blockDim.x + threadIdx.x;
    if (t >= n_quads) return;
    int n = t << 2;                      // first element index (multiple of 4)
    int j = (n >> 12) & 7;               // wire-3 digit (post = 4096 = 2^12)
    int jp = (8 - j) & 7;                // source digit
    int src = n + ((jp - j) << 12);      // same a,b; swap j digit

    f32x4 v = __builtin_nontemporal_load(
        reinterpret_cast<const f32x4*>(xr + src));
    __builtin_nontemporal_store(v, out + t);
}

__global__ void Xd_cplx_kernel(const float* __restrict__ xr,
                               const float* __restrict__ xi,
                               float4* __restrict__ out,
                               int n_pairs /* N/2 */) {
    int t = blockIdx.x * blockDim.x + threadIdx.x;
    if (t >= n_pairs) return;
    int n = t << 1;
    int j = (n >> 12) & 7;
    int jp = (8 - j) & 7;
    int src = n + ((jp - j) << 12);

    float2 r  = *reinterpret_cast<const float2*>(xr + src);
    float2 im = *reinterpret_cast<const float2*>(xi + src);
    out[t] = make_float4(r.x, im.x, r.y, im.y);
}

extern "C" void kernel_launch(void* const* d_in, const int* in_sizes, int n_in,
                              void* d_out, int out_size, void* d_ws, size_t ws_size,
                              hipStream_t stream) {
    const float* xr = (const float*)d_in[0];
    const float* xi = (const float*)d_in[1];

    int N = in_sizes[0];                 // 8^8 = 16,777,216
    int block = 256;

    if (out_size == N) {
        // float32 output: permuted real plane only (64 MB in + 64 MB out)
        int n_quads = N >> 2;
        int grid = (n_quads + block - 1) / block;
        Xd_real_kernel<<<grid, block, 0, stream>>>(xr, (f32x4*)d_out, n_quads);
    } else {
        // interleaved complex64 output (out_size == 2N floats)
        int n_pairs = N >> 1;
        int grid = (n_pairs + block - 1) / block;
        Xd_cplx_kernel<<<grid, block, 0, stream>>>(xr, xi, (float4*)d_out, n_pairs);
    }
}